// Round 4
// baseline (277.665 us; speedup 1.0000x reference)
//
#include <hip/hip_runtime.h>
#include <math.h>

// Chamfer k-NN (k=16, L2), R4: norm-trick (3-FMA distance) + 4 slices +
// float4 (x,y,z,|r|^2) packed points + conflict-free deferred queue.
// kernel0 (pack): pred4 = pack(src+flow), tgt4 = pack(tgt), w = |p|^2.
// kernel1 (knn): grid (q-chunk=256, NSLICE=4, B*2). 2048-ref slice staged in
//          LDS as float4; hot loop: 1 broadcast ds_read_b128 + 3 FMA + masked
//          enqueue into qbuf[cnt*256+tid]. Drain (sorted-16 chain insert) when
//          any lane has >=8 queued. Adjusted values c = d2 - |q|^2; +q2 on out.
// kernel2 (merge): merge 4 sorted per-slice top-16 lists, sqrt, mean, atomic.

#define INFV    3.0e38f
#define NSLICE  4
#define MAXSLEN 2048

__device__ __forceinline__ void chain_insert(float (&s)[16], float v) {
#pragma unroll
    for (int z = 0; z < 16; ++z) {
        float lo = fminf(s[z], v);
        v        = fmaxf(s[z], v);
        s[z] = lo;
    }
}

__global__ __launch_bounds__(256) void pack_kernel(
    const float* __restrict__ src, const float* __restrict__ tgt,
    const float* __restrict__ flow,
    float4* __restrict__ pred4, float4* __restrict__ tgt4,
    int BN, int BM)
{
    int i = blockIdx.x * 256 + threadIdx.x;
    if (i < BN) {
        float x = src[3 * i + 0] + flow[3 * i + 0];
        float y = src[3 * i + 1] + flow[3 * i + 1];
        float z = src[3 * i + 2] + flow[3 * i + 2];
        pred4[i] = make_float4(x, y, z, fmaf(x, x, fmaf(y, y, z * z)));
    }
    if (i < BM) {
        float x = tgt[3 * i + 0];
        float y = tgt[3 * i + 1];
        float z = tgt[3 * i + 2];
        tgt4[i] = make_float4(x, y, z, fmaf(x, x, fmaf(y, y, z * z)));
    }
}

__global__ __launch_bounds__(256, 2) void knn_slice_kernel(
    const float4* __restrict__ pred4,  // [B][N] (x,y,z,|p|^2)
    const float4* __restrict__ tgt4,   // [B][M]
    float* __restrict__ topk,          // [totalInst][NSLICE][16] true d2, sorted
    int N, int M)
{
    __shared__ float4 tile[MAXSLEN];      // 32 KB: ref slice
    __shared__ float  qbuf[16 * 256];     // 16 KB: per-thread queues, stride 256

    const int tid   = threadIdx.x;
    const int slice = blockIdx.y;
    const int z     = blockIdx.z;          // b*2 + dir
    const int b     = z >> 1, dir = z & 1;

    const int nq   = dir ? M : N;
    const int nref = dir ? N : M;
    const int qi   = blockIdx.x * 256 + tid;
    const long instBase = (long)((z >= 1 ? N : 0) + (z >= 2 ? M : 0) + (z >= 3 ? N : 0));

    const float4* qp = (dir ? tgt4 : pred4) + (size_t)b * nq;
    const float4* rp = (dir ? pred4 : tgt4) + (size_t)b * nref;

    const int slen = nref / NSLICE;
    const int base = slice * slen;
    const int jend = (slice == NSLICE - 1) ? (nref - base) : slen;
    const float4* rs = rp + base;

    // ---- stage slice into LDS (coalesced float4) ----
    for (int i = tid; i < jend; i += 256) tile[i] = rs[i];

    const bool valid = qi < nq;
    float nx = 0.f, ny = 0.f, nz = 0.f, q2 = 0.f;
    if (valid) {
        float4 q = qp[qi];
        nx = -2.0f * q.x; ny = -2.0f * q.y; nz = -2.0f * q.z; q2 = q.w;
    }

    __syncthreads();

    float s[16];
#pragma unroll
    for (int i = 0; i < 16; ++i) s[i] = INFV;
    float tau = valid ? INFV : -INFV;      // invalid lanes never enqueue
    int   cnt = 0;

#define DRAIN() {                                                   \
        for (int i = 0;; ++i) {                                     \
            if (!__ballot(i < cnt)) break;                          \
            float v = (i < cnt) ? qbuf[i * 256 + tid] : INFV;       \
            chain_insert(s, v);                                     \
        }                                                           \
        cnt = 0;                                                    \
        tau = valid ? s[15] : -INFV;                                \
    }

#define PROC(r) {                                                   \
        float c = fmaf(nx, (r).x, fmaf(ny, (r).y,                   \
                   fmaf(nz, (r).z, (r).w)));                        \
        if (c < tau) { qbuf[cnt * 256 + tid] = c; cnt++; }          \
    }

    int j = 0;
    for (; j + 8 <= jend; j += 8) {
#pragma unroll
        for (int u = 0; u < 8; ++u) {
            float4 r = tile[j + u];        // broadcast ds_read_b128
            PROC(r)
        }
        if (__ballot(cnt >= 8)) DRAIN();   // cap 16: max cnt 7+8 = 15
    }
    for (; j < jend; ++j) {
        float4 r = tile[j];
        PROC(r)
    }
    DRAIN();                               // final

#undef PROC
#undef DRAIN

    if (valid) {
        float* o = topk + ((size_t)(instBase + qi) * NSLICE + slice) * 16;
#pragma unroll
        for (int i = 0; i < 16; ++i) o[i] = s[i] + q2;   // true d2, still sorted
    }
}

__global__ __launch_bounds__(256) void merge_topk_kernel(
    const float* __restrict__ topk, float* __restrict__ out,
    int totalInst, float scale)
{
    const int inst = blockIdx.x * 256 + threadIdx.x;
    float acc = 0.0f;
    if (inst < totalInst) {
        float s[16];
#pragma unroll
        for (int i = 0; i < 16; ++i) s[i] = INFV;
        const float* p = topk + (size_t)inst * (NSLICE * 16);
        for (int sl = 0; sl < NSLICE; ++sl) {
            const float* q = p + sl * 16;
            for (int i = 0; i < 16; ++i) {       // slice list sorted ascending
                float v = q[i];
                if (!(v < s[15])) break;         // rest can't enter top-16
                chain_insert(s, v);
            }
        }
        float sum = 0.0f;
#pragma unroll
        for (int i = 0; i < 16; ++i) sum += sqrtf(fmaxf(s[i], 0.0f));
        acc = sum * (1.0f / 16.0f);
    }
#pragma unroll
    for (int off = 32; off > 0; off >>= 1) acc += __shfl_down(acc, off);
    __shared__ float wsum[4];
    const int lane = threadIdx.x & 63, wid = threadIdx.x >> 6;
    if (lane == 0) wsum[wid] = acc;
    __syncthreads();
    if (threadIdx.x == 0)
        atomicAdd(out, (wsum[0] + wsum[1] + wsum[2] + wsum[3]) * scale);
}

extern "C" void kernel_launch(void* const* d_in, const int* in_sizes, int n_in,
                              void* d_out, int out_size, void* d_ws, size_t ws_size,
                              hipStream_t stream) {
    const float* src  = (const float*)d_in[0];   // pc_source [B,N,3]
    const float* tgt  = (const float*)d_in[1];   // pc_target [B,M,3]
    const float* flow = (const float*)d_in[2];   // pred_flow [B,N,3]
    float* out = (float*)d_out;

    const int B = 2;                              // per reference setup
    const int N = in_sizes[0] / (B * 3);
    const int M = in_sizes[1] / (B * 3);
    const int BN = B * N, BM = B * M;

    // workspace layout: pred4 | tgt4 | topk
    float4* pred4 = (float4*)d_ws;
    float4* tgt4  = pred4 + BN;
    float*  topk  = (float*)(tgt4 + BM);          // 2*(N+M)*NSLICE*16 floats

    hipMemsetAsync(out, 0, out_size * sizeof(float), stream);

    int maxBP = (BN > BM) ? BN : BM;
    pack_kernel<<<(maxBP + 255) / 256, 256, 0, stream>>>(
        src, tgt, flow, pred4, tgt4, BN, BM);

    int maxq = (N > M) ? N : M;
    dim3 grid1((maxq + 255) / 256, NSLICE, 2 * B);
    knn_slice_kernel<<<grid1, 256, 0, stream>>>(pred4, tgt4, topk, N, M);

    int totalInst = 2 * (N + M);
    float scale = 1.0f / ((float)B * (float)N);
    merge_topk_kernel<<<(totalInst + 255) / 256, 256, 0, stream>>>(
        topk, out, totalInst, scale);
}

// Round 5
// 174.740 us; speedup vs baseline: 1.5890x; 1.5890x over previous
//
#include <hip/hip_runtime.h>
#include <math.h>

// Chamfer k-NN (k=16, L2), R5: NSLICE=8 (occupancy 4 blk/CU) + norm-trick
// 3-FMA distance + batched bitonic drain (sort8 + bitonic halver/merge into
// sorted s[16]) replacing the per-value chain insert.
// kernel0 (pack): pred4=(src+flow,|.|^2), tgt4=(tgt,|.|^2); zeroes out[0].
// kernel1 (knn):  grid (32 q-chunks, 8 slices, B*2). 1024-ref slice in LDS;
//                 hot loop: bcast ds_read_b128 + 3 FMA + cmp + masked enqueue
//                 into qbuf[cnt*256+tid] (conflict-free). Drain when any lane
//                 has >=8 queued, in fixed batches of 8.
// kernel2 (merge): merge 8 sorted per-slice top-16 lists, sqrt, mean, atomic.

#define INFV    3.0e38f
#define NSLICE  8
#define SLEN    1024

__device__ __forceinline__ void ce(float& a, float& b) {
    float lo = fminf(a, b);
    b = fmaxf(a, b);
    a = lo;
}

// Merge up to 8 queued values (qb[(base+i)*256], i<cnt-base) into sorted s[16].
__device__ __forceinline__ void drain_batch(float (&s)[16], const float* qb,
                                            int base, int cnt)
{
    float q[8];
#pragma unroll
    for (int i = 0; i < 8; ++i) {
        float v = qb[(base + i) * 256];
        q[i] = (base + i < cnt) ? v : INFV;
    }
    // sort8 ascending — Batcher odd-even, 19 CE
    ce(q[0],q[1]); ce(q[2],q[3]); ce(q[4],q[5]); ce(q[6],q[7]);
    ce(q[0],q[2]); ce(q[1],q[3]); ce(q[4],q[6]); ce(q[5],q[7]);
    ce(q[1],q[2]); ce(q[5],q[6]);
    ce(q[0],q[4]); ce(q[1],q[5]); ce(q[2],q[6]); ce(q[3],q[7]);
    ce(q[2],q[4]); ce(q[3],q[5]);
    ce(q[1],q[2]); ce(q[3],q[4]); ce(q[5],q[6]);
    // bitonic halver: lowest-16 of s(asc,16) ++ qdesc(16, INF-padded)
    // -> s[0..7] unchanged, s[8+i] = min(s[8+i], q[7-i]); result is bitonic
#pragma unroll
    for (int i = 0; i < 8; ++i) s[8 + i] = fminf(s[8 + i], q[7 - i]);
    // bitonic merge-sort of bitonic-16: stages d = 8,4,2,1 (32 CE)
    ce(s[0],s[8]);  ce(s[1],s[9]);  ce(s[2],s[10]); ce(s[3],s[11]);
    ce(s[4],s[12]); ce(s[5],s[13]); ce(s[6],s[14]); ce(s[7],s[15]);
    ce(s[0],s[4]);  ce(s[1],s[5]);  ce(s[2],s[6]);  ce(s[3],s[7]);
    ce(s[8],s[12]); ce(s[9],s[13]); ce(s[10],s[14]);ce(s[11],s[15]);
    ce(s[0],s[2]);  ce(s[1],s[3]);  ce(s[4],s[6]);  ce(s[5],s[7]);
    ce(s[8],s[10]); ce(s[9],s[11]); ce(s[12],s[14]);ce(s[13],s[15]);
    ce(s[0],s[1]);  ce(s[2],s[3]);  ce(s[4],s[5]);  ce(s[6],s[7]);
    ce(s[8],s[9]);  ce(s[10],s[11]);ce(s[12],s[13]);ce(s[14],s[15]);
}

__global__ __launch_bounds__(256) void pack_kernel(
    const float* __restrict__ src, const float* __restrict__ tgt,
    const float* __restrict__ flow,
    float4* __restrict__ pred4, float4* __restrict__ tgt4,
    float* __restrict__ out, int BN, int BM)
{
    int i = blockIdx.x * 256 + threadIdx.x;
    if (i == 0) out[0] = 0.0f;                 // replaces memset (poisoned 0xAA)
    if (i < BN) {
        float x = src[3 * i + 0] + flow[3 * i + 0];
        float y = src[3 * i + 1] + flow[3 * i + 1];
        float z = src[3 * i + 2] + flow[3 * i + 2];
        pred4[i] = make_float4(x, y, z, fmaf(x, x, fmaf(y, y, z * z)));
    }
    if (i < BM) {
        float x = tgt[3 * i + 0];
        float y = tgt[3 * i + 1];
        float z = tgt[3 * i + 2];
        tgt4[i] = make_float4(x, y, z, fmaf(x, x, fmaf(y, y, z * z)));
    }
}

__global__ __launch_bounds__(256, 4) void knn_slice_kernel(
    const float4* __restrict__ pred4,  // [B][N] (x,y,z,|p|^2)
    const float4* __restrict__ tgt4,   // [B][M]
    float* __restrict__ topk,          // [totalInst][NSLICE][16] true d2, sorted
    int N, int M)
{
    __shared__ float4 tile[SLEN];         // 16 KB ref slice
    __shared__ float  qbuf[16 * 256];     // 16 KB per-thread queues, stride 256

    const int tid   = threadIdx.x;
    const int slice = blockIdx.y;
    const int z     = blockIdx.z;          // b*2 + dir
    const int b     = z >> 1, dir = z & 1;

    const int nq   = dir ? M : N;
    const int nref = dir ? N : M;
    const int qi   = blockIdx.x * 256 + tid;
    const long instBase = (long)((z >= 1 ? N : 0) + (z >= 2 ? M : 0) + (z >= 3 ? N : 0));

    const float4* qp = (dir ? tgt4 : pred4) + (size_t)b * nq;
    const float4* rp = (dir ? pred4 : tgt4) + (size_t)b * nref;

    const int slen = nref / NSLICE;        // 1024
    const int base = slice * slen;
    const int jend = (slice == NSLICE - 1) ? (nref - base) : slen;
    const float4* rs = rp + base;

    for (int i = tid; i < jend; i += 256) tile[i] = rs[i];

    const bool valid = qi < nq;
    float nx = 0.f, ny = 0.f, nz = 0.f, q2 = 0.f;
    if (valid) {
        float4 q = qp[qi];
        nx = -2.0f * q.x; ny = -2.0f * q.y; nz = -2.0f * q.z; q2 = q.w;
    }

    __syncthreads();

    float s[16];
#pragma unroll
    for (int i = 0; i < 16; ++i) s[i] = INFV;
    float tau = valid ? INFV : -INFV;      // invalid lanes never enqueue
    int   cnt = 0;
    const float* qb_tid = qbuf + tid;

#define DRAIN_ALL() {                                               \
        drain_batch(s, qb_tid, 0, cnt);                             \
        if (__ballot(cnt > 8)) drain_batch(s, qb_tid, 8, cnt);      \
        cnt = 0;                                                    \
        tau = valid ? s[15] : -INFV;                                \
    }

    int j = 0;
    for (; j + 8 <= jend; j += 8) {
        float4 w[8];
#pragma unroll
        for (int u = 0; u < 8; ++u) w[u] = tile[j + u];   // broadcast b128
#pragma unroll
        for (int u = 0; u < 8; ++u) {
            float c = fmaf(nx, w[u].x,
                      fmaf(ny, w[u].y,
                      fmaf(nz, w[u].z, w[u].w)));
            if (c < tau) { qbuf[cnt * 256 + tid] = c; cnt++; }
        }
        if (__ballot(cnt >= 8)) DRAIN_ALL();   // cap 16: max cnt 7+8 = 15
    }
    for (; j < jend; ++j) {                    // generic tail (unused at 1024)
        float4 r = tile[j];
        float c = fmaf(nx, r.x, fmaf(ny, r.y, fmaf(nz, r.z, r.w)));
        if (c < tau) { qbuf[cnt * 256 + tid] = c; cnt++; }
    }
    if (__ballot(cnt > 0)) DRAIN_ALL();        // final

#undef DRAIN_ALL

    if (valid) {
        float* o = topk + ((size_t)(instBase + qi) * NSLICE + slice) * 16;
#pragma unroll
        for (int i = 0; i < 16; ++i) o[i] = s[i] + q2;   // true d2, still sorted
    }
}

__device__ __forceinline__ void chain_insert(float (&s)[16], float v) {
#pragma unroll
    for (int z = 0; z < 16; ++z) {
        float lo = fminf(s[z], v);
        v        = fmaxf(s[z], v);
        s[z] = lo;
    }
}

__global__ __launch_bounds__(256) void merge_topk_kernel(
    const float* __restrict__ topk, float* __restrict__ out,
    int totalInst, float scale)
{
    const int inst = blockIdx.x * 256 + threadIdx.x;
    float acc = 0.0f;
    if (inst < totalInst) {
        float s[16];
#pragma unroll
        for (int i = 0; i < 16; ++i) s[i] = INFV;
        const float* p = topk + (size_t)inst * (NSLICE * 16);
        for (int sl = 0; sl < NSLICE; ++sl) {
            const float* q = p + sl * 16;
            for (int i = 0; i < 16; ++i) {       // slice list sorted ascending
                float v = q[i];
                if (!(v < s[15])) break;         // rest can't enter top-16
                chain_insert(s, v);
            }
        }
        float sum = 0.0f;
#pragma unroll
        for (int i = 0; i < 16; ++i) sum += sqrtf(fmaxf(s[i], 0.0f));
        acc = sum * (1.0f / 16.0f);
    }
#pragma unroll
    for (int off = 32; off > 0; off >>= 1) acc += __shfl_down(acc, off);
    __shared__ float wsum[4];
    const int lane = threadIdx.x & 63, wid = threadIdx.x >> 6;
    if (lane == 0) wsum[wid] = acc;
    __syncthreads();
    if (threadIdx.x == 0)
        atomicAdd(out, (wsum[0] + wsum[1] + wsum[2] + wsum[3]) * scale);
}

extern "C" void kernel_launch(void* const* d_in, const int* in_sizes, int n_in,
                              void* d_out, int out_size, void* d_ws, size_t ws_size,
                              hipStream_t stream) {
    const float* src  = (const float*)d_in[0];   // pc_source [B,N,3]
    const float* tgt  = (const float*)d_in[1];   // pc_target [B,M,3]
    const float* flow = (const float*)d_in[2];   // pred_flow [B,N,3]
    float* out = (float*)d_out;

    const int B = 2;                              // per reference setup
    const int N = in_sizes[0] / (B * 3);
    const int M = in_sizes[1] / (B * 3);
    const int BN = B * N, BM = B * M;

    // workspace layout: pred4 | tgt4 | topk
    float4* pred4 = (float4*)d_ws;
    float4* tgt4  = pred4 + BN;
    float*  topk  = (float*)(tgt4 + BM);          // 2*(N+M)*NSLICE*16 floats

    int maxBP = (BN > BM) ? BN : BM;
    pack_kernel<<<(maxBP + 255) / 256, 256, 0, stream>>>(
        src, tgt, flow, pred4, tgt4, out, BN, BM);

    int maxq = (N > M) ? N : M;
    dim3 grid1((maxq + 255) / 256, NSLICE, 2 * B);
    knn_slice_kernel<<<grid1, 256, 0, stream>>>(pred4, tgt4, topk, N, M);

    int totalInst = 2 * (N + M);
    float scale = 1.0f / ((float)B * (float)N);
    merge_topk_kernel<<<(totalInst + 255) / 256, 256, 0, stream>>>(
        topk, out, totalInst, scale);
}